// Round 15
// baseline (188.619 us; speedup 1.0000x reference)
//
#include <hip/hip_runtime.h>
#include <hip/hip_bf16.h>

#define TT 336
#define NF 321
#define NB 64
#define NSER (NB * NF)   // 20544 series
#define WPB 4            // waves (series) per block in patch kernels
#define KP 352           // K padded to multiple of 32 for 16x16x32 MFMA
#define LDA 360          // LDS row stride (ushorts) in psd_k
#define SPB 16           // series per block in psd_k
#define NPSB (NSER / SPB)    // 1284 logical psd blocks
#define NPSBG 1288           // dispatched psd blocks (8 x 161, guard skips 4)
#define NPATB (NSER / WPB)   // 5136 patch blocks (divisible by 8)
#define TSP (TT + 4)     // padded ts row stride (float2): 680 words % 32 = 8

// prefix-table skew: breaks stride-P bank conflicts (P=16/32 worst cases)
#define SK(b) ((b) + ((b) >> 5))
#define TBL 348          // >= SK(336)+1 = 347

// transpose grid (fallback paths): 11 x 11 x 64 blocks
#define TGX 11
#define TGY 11
#define NMSEP (TGX * TGY * NB)   // 7744 per-block MSE partials (fallback)

typedef __attribute__((ext_vector_type(8))) short bf16x8;
typedef __attribute__((ext_vector_type(4))) float f32x4;
typedef unsigned long long ULL;

__device__ __forceinline__ unsigned short f2bf(float v) {
    unsigned x = __float_as_uint(v);
    x += 0x7FFFu + ((x >> 16) & 1u);   // RNE; inputs are finite
    return (unsigned short)(x >> 16);
}

// sorted-3 insert (a0 >= a1 >= a2)
__device__ __forceinline__ void ins3(ULL& a0, ULL& a1, ULL& a2, ULL x) {
    ULL hi = a0 > x ? a0 : x;
    ULL lo = a0 > x ? x : a0;
    a0 = hi;
    ULL hi1 = a1 > lo ? a1 : lo;
    ULL lo1 = a1 > lo ? lo : a1;
    a1 = hi1;
    a2 = a2 > lo1 ? a2 : lo1;
}

// ---------------------------------------------------------------------------
// Twiddle matrix: Wb[n][k], n=2(f-1) -> cos(2pi f k/336), n=2(f-1)+1 -> sin.
// fp32 trig: output is bf16 (8 mantissa bits) -> fp32 accuracy is exact here.
// ---------------------------------------------------------------------------
__global__ void twiddle_k(unsigned short* __restrict__ Wb) {
    int n = blockIdx.x;          // 0..335
    int f = (n >> 1) + 1;
    int isSin = n & 1;
    for (int k = threadIdx.x; k < KP; k += blockDim.x) {
        float v = 0.0f;
        if (k < TT) {
            int r = (f * k) % TT;
            float ang = 6.2831853071795864769f * (float)r / 336.0f;
            v = isSin ? sinf(ang) : cosf(ang);
        }
        Wb[(size_t)n * KP + k] = f2bf(v);
    }
}

// ---------------------------------------------------------------------------
// PSD + top-3 via MFMA GEMM. Block = 16 series, 4 waves split 21 nt-tiles
// (5/5/5/6). Round-15: (a) XCD-aware swizzle so adjacent series-strips
// (which share 64B lines; NF=321 so strips are unaligned) land on the same
// XCD's L2 — r7 showed 1.5x over-fetch without it; (b) staging unrolled in
// 11+10 batches + __launch_bounds__(256,6) to cut VGPRs so all 1284 blocks
// are co-resident (6 blocks/CU) instead of a 1.26-round dispatch tail.
// ---------------------------------------------------------------------------
__global__ __launch_bounds__(256, 6) void psd_k(const float* __restrict__ tgO,
                                                const unsigned short* __restrict__ Wb,
                                                uint4* __restrict__ topk) {
    __shared__ __align__(16) unsigned short sA[SPB][LDA];
    __shared__ ULL tk3[4][SPB][3];
    const int tid = threadIdx.x;
    const int lb = (blockIdx.x & 7) * 161 + (blockIdx.x >> 3);
    if (lb >= NPSB) return;
    const int serBase = lb * SPB;

    {
        int f_l = tid & 15, tch = tid >> 4;   // 16 t-chunks of 21
        int ser = serBase + f_l;
        int bb = ser / NF, ff = ser - bb * NF;
        const float* base = tgO + (size_t)bb * TT * NF + ff;
        int t0 = tch * 21;
        float v[11];
#pragma unroll
        for (int i = 0; i < 11; i++) v[i] = base[(size_t)(t0 + i) * NF];
#pragma unroll
        for (int i = 0; i < 11; i++) sA[f_l][t0 + i] = f2bf(v[i]);
        float u[10];
#pragma unroll
        for (int i = 0; i < 10; i++) u[i] = base[(size_t)(t0 + 11 + i) * NF];
#pragma unroll
        for (int i = 0; i < 10; i++) sA[f_l][t0 + 11 + i] = f2bf(u[i]);
    }
    if (tid < SPB * 16) sA[tid >> 4][TT + (tid & 15)] = 0;   // K padding
    __syncthreads();

    const int wave = tid >> 6, lane = tid & 63;
    const int quad = lane >> 4, c = lane & 15;
    const unsigned short* aRow = &sA[c][quad * 8];   // A[m=c][k=quad*8+j]
    const int ntStart = wave * 5;
    const int ntEnd = (wave == 3) ? 21 : ntStart + 5;

    ULL t0k[4] = {0, 0, 0, 0}, t1k[4] = {0, 0, 0, 0}, t2k[4] = {0, 0, 0, 0};
    for (int nt = ntStart; nt < ntEnd; nt++) {
        const unsigned short* bRow = Wb + (size_t)(nt * 16 + c) * KP + quad * 8;
        f32x4 acc = (f32x4){0.f, 0.f, 0.f, 0.f};
#pragma unroll
        for (int ks = 0; ks < 11; ks++) {
            bf16x8 a = *(const bf16x8*)(aRow + ks * 32);
            bf16x8 b = *(const bf16x8*)(bRow + ks * 32);
            acc = __builtin_amdgcn_mfma_f32_16x16x32_bf16(a, b, acc, 0, 0, 0);
        }
        int n = nt * 16 + c;
        unsigned fidx = (unsigned)((n >> 1) + 1);
        unsigned ftag = 0xFFFFFFFFu - fidx;
        bool odd = (n & 1) != 0;
#pragma unroll
        for (int r = 0; r < 4; r++) {
            float v = acc[r];
            float p = v * v;
            p += __shfl_xor(p, 1, 64);            // pair cos/sin columns
            ULL key = odd ? 0ull
                          : (((ULL)__float_as_uint(p) << 32) | (ULL)ftag);
            ins3(t0k[r], t1k[r], t2k[r], key);
        }
    }
#pragma unroll
    for (int m = 2; m <= 8; m <<= 1) {
#pragma unroll
        for (int r = 0; r < 4; r++) {
            ULL b0 = __shfl_xor(t0k[r], m, 64);
            ULL b1 = __shfl_xor(t1k[r], m, 64);
            ULL b2 = __shfl_xor(t2k[r], m, 64);
            ins3(t0k[r], t1k[r], t2k[r], b0);
            ins3(t0k[r], t1k[r], t2k[r], b1);
            ins3(t0k[r], t1k[r], t2k[r], b2);
        }
    }
    if (c == 0) {
#pragma unroll
        for (int r = 0; r < 4; r++) {
            int s = quad * 4 + r;
            tk3[wave][s][0] = t0k[r];
            tk3[wave][s][1] = t1k[r];
            tk3[wave][s][2] = t2k[r];
        }
    }
    __syncthreads();
    if (tid < SPB) {
        ULL k0 = 0, k1 = 0, k2 = 0;
#pragma unroll
        for (int wv = 0; wv < 4; wv++) {
#pragma unroll
            for (int j = 0; j < 3; j++) ins3(k0, k1, k2, tk3[wv][tid][j]);
        }
        unsigned f0 = 0xFFFFFFFFu - (unsigned)(k0 & 0xFFFFFFFFull);
        unsigned f1 = 0xFFFFFFFFu - (unsigned)(k1 & 0xFFFFFFFFull);
        unsigned f2 = 0xFFFFFFFFu - (unsigned)(k2 & 0xFFFFFFFFull);
        topk[serBase + tid] = make_uint4(f0, f1, f2, 0u);
    }
}

// ---------------------------------------------------------------------------
// FALLBACK Kernel: transpose [B,T,F] -> float2{tg,fc}[B*F][T], fused MSE.
// ---------------------------------------------------------------------------
__global__ __launch_bounds__(256) void transpose_k(const float* __restrict__ fc,
                                                   const float* __restrict__ tg,
                                                   float2* __restrict__ out,
                                                   double* __restrict__ msep,
                                                   double* __restrict__ acc) {
    __shared__ float ta[32][33];
    __shared__ float tb[32][33];
    __shared__ double wacc[4];
    const int b = blockIdx.z;
    const int t0 = blockIdx.x * 32, f0 = blockIdx.y * 32;
    const int tx = threadIdx.x, ty = threadIdx.y;   // block (32, 8)
    const size_t base = (size_t)b * TT * NF;
    double ms = 0.0;
#pragma unroll
    for (int k = 0; k < 4; k++) {
        int t = t0 + ty + 8 * k, f = f0 + tx;
        if (t < TT && f < NF) {
            float a = tg[base + (size_t)t * NF + f];
            float c = fc[base + (size_t)t * NF + f];
            ta[ty + 8 * k][tx] = a;
            tb[ty + 8 * k][tx] = c;
            double d = (double)a - (double)c;
            ms += d * d;
        }
    }
    __syncthreads();
#pragma unroll
    for (int k = 0; k < 4; k++) {
        int f = f0 + ty + 8 * k, t = t0 + tx;
        if (t < TT && f < NF) {
            out[((size_t)b * NF + f) * TT + t] =
                make_float2(ta[tx][ty + 8 * k], tb[tx][ty + 8 * k]);
        }
    }
    for (int off = 32; off; off >>= 1) ms += __shfl_down(ms, off, 64);
    int flat = ty * 32 + tx;
    int lane = flat & 63, wid = flat >> 6;
    if (lane == 0) wacc[wid] = ms;
    __syncthreads();
    if (flat == 0) {
        double tot = wacc[0] + wacc[1] + wacc[2] + wacc[3];
        if (msep) {
            int blk = (blockIdx.z * TGY + blockIdx.y) * TGX + blockIdx.x;
            msep[blk] = tot;
        } else {
            atomicAdd(&acc[0], tot);
        }
    }
}

// ---------------------------------------------------------------------------
__global__ void mse_k(const float* __restrict__ fc, const float* __restrict__ tg,
                      double* __restrict__ acc) {
    const size_t N4 = (size_t)NB * TT * NF / 4;
    const float4* a4 = (const float4*)fc;
    const float4* b4 = (const float4*)tg;
    double s = 0.0;
    for (size_t i = (size_t)blockIdx.x * blockDim.x + threadIdx.x; i < N4;
         i += (size_t)gridDim.x * blockDim.x) {
        float4 a = a4[i], b = b4[i];
        double d0 = (double)a.x - (double)b.x;
        double d1 = (double)a.y - (double)b.y;
        double d2 = (double)a.z - (double)b.z;
        double d3 = (double)a.w - (double)b.w;
        s += d0 * d0 + d1 * d1 + d2 * d2 + d3 * d3;
    }
    for (int off = 32; off; off >>= 1) s += __shfl_down(s, off, 64);
    __shared__ double wsum[4];
    int flat = threadIdx.x;
    int lane = flat & 63, wid = flat >> 6;
    if (lane == 0) wsum[wid] = s;
    __syncthreads();
    if (flat == 0) atomicAdd(&acc[0], wsum[0] + wsum[1] + wsum[2] + wsum[3]);
}

// ---------------------------------------------------------------------------
// Full-fp64 patch loss (fallback path — exact reference mirror)
// ---------------------------------------------------------------------------
__device__ __forceinline__ double patch_loss(double S1, double S2, double S3,
                                             double S4, double S5, double nn) {
    double mt = S1 / nn, mf = S2 / nn;
    double tvs = S3 - nn * mt * mt; tvs = tvs > 0.0 ? tvs : 0.0;
    double fvs = S4 - nn * mf * mf; fvs = fvs > 0.0 ? fvs : 0.0;
    double num = S5 - nn * mt * mf;
    double corr = num / (sqrt(tvs * fvs) + 1e-8);
    double closs = 1.0 - fabs(corr);
    double tvar = tvs / (nn - 1.0), fvar = fvs / (nn - 1.0);
    double vloss = fabs(tvar - fvar) / (tvar + 1e-8);
    double mloss = fabs(mt - mf) / (fabs(mt) + 1e-8);
    return closs + vloss + mloss;
}

// ---------------------------------------------------------------------------
// Round-10 fast patch loss: closs/vloss fp32, mloss fp64 (one fp64 divide).
// ---------------------------------------------------------------------------
__device__ __forceinline__ double patch_loss_fast(double S1, double S2,
                                                  float S3, float S4, float S5,
                                                  int n) {
    float nnf = (float)n;
    float invf = 1.0f / nnf;
    float s1f = (float)S1, s2f = (float)S2;
    float tvs = S3 - s1f * s1f * invf; tvs = tvs > 0.f ? tvs : 0.f;
    float fvs = S4 - s2f * s2f * invf; fvs = fvs > 0.f ? fvs : 0.f;
    float num = S5 - s1f * s2f * invf;
    float corr = num / (sqrtf(tvs * fvs) + 1e-8f);
    float closs = 1.0f - fabsf(corr);
    float vloss = fabsf(tvs - fvs) / (tvs + (nnf - 1.0f) * 1e-8f);
    double mloss = fabs(S1 - S2) / (fabs(S1) + (double)n * 1e-8);
    return (double)(closs + vloss) + mloss;
}

// ---------------------------------------------------------------------------
struct PatchCfg {
    int P[3], nseg[3], rs[3];
    bool vp[3], hr[3];
};

__device__ __forceinline__ void make_cfg(int fr0, int fr1, int fr2, PatchCfg& c) {
    c.P[0] = TT / fr0; c.P[1] = TT / fr1; c.P[2] = TT / fr2;
    c.vp[0] = (c.P[0] >= 5);
    c.vp[1] = (c.P[1] >= 5) && (c.P[1] != c.P[0]);
    c.vp[2] = (c.P[2] >= 5) && (c.P[2] != c.P[0]) && (c.P[2] != c.P[1]);
#pragma unroll
    for (int q = 0; q < 3; q++) {
        c.nseg[q] = TT / c.P[q];
        c.rs[q] = c.nseg[q] * c.P[q];
        c.hr[q] = c.vp[q] && ((TT - c.rs[q]) >= 5);
    }
}

// slot i in [0,204) -> (s,e,kept) with dedup against earlier periods
__device__ __forceinline__ bool slot_patch(const PatchCfg& c, int i, int& s, int& e) {
    bool kept = false;
    s = 0; e = 0;
    if (i < 204) {
        int k = (i >= 136) ? 2 : ((i >= 68) ? 1 : 0);
        int si = i - k * 68;
        if (c.vp[k]) {
            if (si < c.nseg[k]) { s = c.P[k] * si; e = s + c.P[k]; kept = true; }
            else if (si == c.nseg[k] && c.hr[k]) { s = c.rs[k]; e = TT; kept = true; }
            if (kept) {
#pragma unroll
                for (int j = 0; j < 2; j++) {
                    if (j < k && c.vp[j]) {
                        bool dup = (s == c.rs[j]) && (e == TT) && c.hr[j];
                        int len = e - s;
                        if (len == c.P[j] && s < c.rs[j] && (s % c.P[j]) == 0) dup = true;
                        if (dup) kept = false;
                    }
                }
            }
        }
    }
    return kept;
}

// ---------------------------------------------------------------------------
// Kernel (round-10 verified body): patch stats from ORIGINAL layout with
// fused MSE. XCD swizzle; ts rows padded to TSP; S1,S2 fp64 tables;
// S3..S5 fp32. Epilogue: block-level LDS reduce -> ONE (ls,lc,ms) triple.
// ---------------------------------------------------------------------------
__global__ __launch_bounds__(256) void patch_k(const float* __restrict__ fcO,
                                               const float* __restrict__ tgO,
                                               const uint4* __restrict__ topk,
                                               double* __restrict__ blkout) {
    __shared__ __align__(16) char smem[2 * WPB * TBL * 8 + 3 * WPB * TBL * 4];
    double (*d1)[TBL] = (double(*)[TBL])smem;
    double (*d2)[TBL] = (double(*)[TBL])(smem + WPB * TBL * 8);
    char* regB = smem + 2 * WPB * TBL * 8;
    float2* tsB = (float2*)regB;                   // rows of stride TSP
    float (*t3)[TBL] = (float(*)[TBL])regB;
    float (*t4)[TBL] = (float(*)[TBL])(regB + WPB * TBL * 4);
    float (*t5)[TBL] = (float(*)[TBL])(regB + 2 * WPB * TBL * 4);
    __shared__ double wms[WPB], wls[WPB], wlc[WPB];

    const int tid = threadIdx.x;
    const int w = tid >> 6, lane = tid & 63;
    const int lb = (blockIdx.x & 7) * (NPATB / 8) + (blockIdx.x >> 3);
    const int ser = lb * WPB + w;

    // ---- cooperative load from original layout + fused MSE ----
    {
        const int j = tid & 3;
        const int serj = lb * WPB + j;
        const int bb = serj / NF, ff = serj - bb * NF;
        const float* tb_ = tgO + (size_t)bb * TT * NF + ff;
        const float* fb_ = fcO + (size_t)bb * TT * NF + ff;
        const int tb0 = tid >> 2;
        float2* row = tsB + j * TSP;
        double ms = 0.0;
#pragma unroll
        for (int i = 0; i < 6; i++) {
            int t = tb0 + 64 * i;
            if (t < TT) {
                float a = tb_[(size_t)t * NF];
                float c = fb_[(size_t)t * NF];
                row[t] = make_float2(a, c);
                double d = (double)a - (double)c;
                ms += d * d;
            }
        }
        for (int off = 32; off; off >>= 1) ms += __shfl_down(ms, off, 64);
        if (lane == 0) wms[w] = ms;
    }
    __syncthreads();

    // ---- each wave pulls its series' 6 elements/lane into registers ----
    float2 loc[6];
    double c1 = 0, c2 = 0;
    float c3 = 0, c4 = 0, c5 = 0;
    if (lane < 56) {
        const float4* lp = (const float4*)(tsB + w * TSP + 6 * lane);  // 48B
        float4 va = lp[0], vb = lp[1], vc = lp[2];
        loc[0] = make_float2(va.x, va.y); loc[1] = make_float2(va.z, va.w);
        loc[2] = make_float2(vb.x, vb.y); loc[3] = make_float2(vb.z, vb.w);
        loc[4] = make_float2(vc.x, vc.y); loc[5] = make_float2(vc.z, vc.w);
#pragma unroll
        for (int i = 0; i < 6; i++) {
            float a = loc[i].x, b = loc[i].y;
            c1 += (double)a; c2 += (double)b;
            c3 = fmaf(a, a, c3); c4 = fmaf(b, b, c4); c5 = fmaf(a, b, c5);
        }
    }

    // ---- inclusive scan over chunk sums (S1,S2 fp64; S3..S5 fp32) ----
    double s1 = c1, s2 = c2;
    float s3 = c3, s4 = c4, s5 = c5;
#pragma unroll
    for (int off = 1; off < 64; off <<= 1) {
        double y1 = __shfl_up(s1, off, 64);
        double y2 = __shfl_up(s2, off, 64);
        float y3 = __shfl_up(s3, off, 64);
        float y4 = __shfl_up(s4, off, 64);
        float y5 = __shfl_up(s5, off, 64);
        if (lane >= off) { s1 += y1; s2 += y2; s3 += y3; s4 += y4; s5 += y5; }
    }

    __syncthreads();   // everyone done reading ts before tables overlay it

    // ---- write per-element prefix table (skewed index) ----
    if (lane == 63) {
        d1[w][SK(0)] = 0.0; d2[w][SK(0)] = 0.0;
        t3[w][SK(0)] = 0.f; t4[w][SK(0)] = 0.f; t5[w][SK(0)] = 0.f;
    }
    if (lane < 56) {
        double r1 = s1 - c1, r2 = s2 - c2;
        float r3 = s3 - c3, r4 = s4 - c4, r5 = s5 - c5;
#pragma unroll
        for (int i = 0; i < 6; i++) {
            float a = loc[i].x, b = loc[i].y;
            r1 += (double)a; r2 += (double)b;
            r3 = fmaf(a, a, r3); r4 = fmaf(b, b, r4); r5 = fmaf(a, b, r5);
            int ix = SK(6 * lane + i + 1);
            d1[w][ix] = r1; d2[w][ix] = r2;
            t3[w][ix] = r3; t4[w][ix] = r4; t5[w][ix] = r5;
        }
    }
    __syncthreads();

    uint4 tk = topk[ser];
    PatchCfg cfg;
    make_cfg((int)tk.x, (int)tk.y, (int)tk.z, cfg);

    double lsum = 0.0, lcnt = 0.0;
    ULL anyMask = 0ull;
#pragma unroll
    for (int rI = 0; rI < 4; rI++) {
        int s, e;
        bool kept = slot_patch(cfg, lane + 64 * rI, s, e);
        ULL bal = __ballot(kept);
        anyMask |= bal;
        if (bal == 0ull) continue;          // wave-uniform early-out
        if (kept) {
            int is = SK(s), ie = SK(e);
            double S1 = d1[w][ie] - d1[w][is];
            double S2 = d2[w][ie] - d2[w][is];
            float S3 = t3[w][ie] - t3[w][is];
            float S4 = t4[w][ie] - t4[w][is];
            float S5 = t5[w][ie] - t5[w][is];
            lsum += patch_loss_fast(S1, S2, S3, S4, S5, e - s);
            lcnt += 1.0;
        }
    }

    if (anyMask == 0ull) {
        if (lane == 0) {
            int ie = SK(TT);
            lsum += patch_loss_fast(d1[w][ie], d2[w][ie], t3[w][ie],
                                    t4[w][ie], t5[w][ie], TT);
            lcnt += 1.0;
        }
    }

    for (int off = 32; off; off >>= 1) {
        lsum += __shfl_down(lsum, off, 64);
        lcnt += __shfl_down(lcnt, off, 64);
    }
    if (lane == 0) { wls[w] = lsum; wlc[w] = lcnt; }
    __syncthreads();
    if (tid == 0) {
        blkout[3 * lb + 0] = wls[0] + wls[1] + wls[2] + wls[3];
        blkout[3 * lb + 1] = wlc[0] + wlc[1] + wlc[2] + wlc[3];
        blkout[3 * lb + 2] = wms[0] + wms[1] + wms[2] + wms[3];
    }
}

// ---------------------------------------------------------------------------
// FALLBACK: self-contained series kernel (VALU DFT + topk + serial patches).
// ---------------------------------------------------------------------------
__device__ __forceinline__ void patch_body(const float2* tsw, int lane,
                                           int fr0, int fr1, int fr2,
                                           double& lsum, double& lcnt) {
    PatchCfg cfg;
    make_cfg(fr0, fr1, fr2, cfg);
    ULL anyMask = 0ull;
#pragma unroll
    for (int rI = 0; rI < 4; rI++) {
        int s, e;
        bool kept = slot_patch(cfg, lane + 64 * rI, s, e);
        anyMask |= __ballot(kept);
        if (kept) {
            double S1 = 0, S2 = 0, S3 = 0, S4 = 0, S5 = 0;
            for (int t = s; t < e; t++) {
                float2 v = tsw[t];
                double a = (double)v.x, b = (double)v.y;
                S1 += a; S2 += b;
                S3 += a * a; S4 += b * b; S5 += a * b;
            }
            lsum += patch_loss(S1, S2, S3, S4, S5, (double)(e - s));
            lcnt += 1.0;
        }
    }
    if (anyMask == 0ull) {
        double S1 = 0, S2 = 0, S3 = 0, S4 = 0, S5 = 0;
        for (int t = lane; t < TT; t += 64) {
            float2 v = tsw[t];
            double a = (double)v.x, b = (double)v.y;
            S1 += a; S2 += b;
            S3 += a * a; S4 += b * b; S5 += a * b;
        }
        for (int off = 32; off; off >>= 1) {
            S1 += __shfl_down(S1, off, 64);
            S2 += __shfl_down(S2, off, 64);
            S3 += __shfl_down(S3, off, 64);
            S4 += __shfl_down(S4, off, 64);
            S5 += __shfl_down(S5, off, 64);
        }
        if (lane == 0) {
            lsum += patch_loss(S1, S2, S3, S4, S5, (double)TT);
            lcnt += 1.0;
        }
    }
}

__global__ __launch_bounds__(256, 6) void series_k(const float2* __restrict__ tsG,
                                                   const float* __restrict__ fcG,
                                                   const float* __restrict__ tgG,
                                                   int transposed,
                                                   double2* __restrict__ pairs,
                                                   double* __restrict__ acc) {
    const int w = threadIdx.x >> 6, lane = threadIdx.x & 63;
    const int ser = blockIdx.x * WPB + w;
    __shared__ float2 ts[WPB][TT];
    __shared__ float4 zb[WPB][84];

    if (transposed) {
        const float2* sp = tsG + (size_t)ser * TT;
        for (int t = lane; t < TT; t += 64) ts[w][t] = sp[t];
    } else {
        int b = ser / NF, f = ser - b * NF;
        const float* tp = tgG + (size_t)b * TT * NF + f;
        const float* fp = fcG + (size_t)b * TT * NF + f;
        for (int t = lane; t < TT; t += 64)
            ts[w][t] = make_float2(tp[(size_t)t * NF], fp[(size_t)t * NF]);
    }
    __syncthreads();

    for (int t = lane; t < 84; t += 64) {
        float x0 = ts[w][t].x, x1 = ts[w][t + 84].x;
        float x2 = ts[w][t + 168].x, x3 = ts[w][t + 252].x;
        float a = x0 + x2, b2 = x1 + x3, c = x0 - x2, d = x1 - x3;
        zb[w][t] = make_float4(a + b2, a - b2, c, d);
    }
    __syncthreads();

    const double TWOPI = 6.283185307179586476925286766559;
    int fb[3] = {1 + lane, 65 + lane, 129 + lane};
    float cc[3], sn[3], re[3], im[3], cd[3], sd[3], sgn[3];
    int selA[3];
#pragma unroll
    for (int q = 0; q < 3; q++) {
        int f = fb[q], cls = f & 3;
        double dl = (double)f * (TWOPI / 336.0);
        cd[q] = (float)cos(dl);
        sd[q] = (float)sin(dl);
        cc[q] = 1.0f; sn[q] = 0.0f; re[q] = 0.0f; im[q] = 0.0f;
        sgn[q] = (cls == 1) ? -1.0f : ((cls == 3) ? 1.0f : 0.0f);
        selA[q] = (cls == 0) ? 0 : ((cls == 2) ? 1 : 2);
    }
    for (int t = 0; t < 84; t++) {
        float4 zv = zb[w][t];
#pragma unroll
        for (int q = 0; q < 3; q++) {
            float zr = (selA[q] == 0) ? zv.x : ((selA[q] == 1) ? zv.y : zv.z);
            float zi = sgn[q] * zv.w;
            re[q] = fmaf(zr, cc[q], re[q]);
            re[q] = fmaf(zi, sn[q], re[q]);
            im[q] = fmaf(zi, cc[q], im[q]);
            im[q] = fmaf(-zr, sn[q], im[q]);
            float nc = fmaf(cc[q], cd[q], -(sn[q] * sd[q]));
            float ns = fmaf(sn[q], cd[q], cc[q] * sd[q]);
            cc[q] = nc; sn[q] = ns;
        }
    }

    ULL k0 = 0, k1 = 0, k2 = 0;
#pragma unroll
    for (int q = 0; q < 3; q++) {
        float a2 = fmaf(re[q], re[q], im[q] * im[q]);
        ULL key = ((ULL)__float_as_uint(a2) << 32) |
                  (ULL)(0xFFFFFFFFu - (unsigned)fb[q]);
        if (fb[q] > 168) key = 0ull;
        ins3(k0, k1, k2, key);
    }
    for (int m = 1; m < 64; m <<= 1) {
        ULL b0 = __shfl_xor(k0, m, 64);
        ULL b1 = __shfl_xor(k1, m, 64);
        ULL b2 = __shfl_xor(k2, m, 64);
        ins3(k0, k1, k2, b0); ins3(k0, k1, k2, b1); ins3(k0, k1, k2, b2);
    }

    int fr0 = (int)(0xFFFFFFFFu - (unsigned)(k0 & 0xFFFFFFFFull));
    int fr1 = (int)(0xFFFFFFFFu - (unsigned)(k1 & 0xFFFFFFFFull));
    int fr2 = (int)(0xFFFFFFFFu - (unsigned)(k2 & 0xFFFFFFFFull));

    double lsum = 0.0, lcnt = 0.0;
    patch_body(&ts[w][0], lane, fr0, fr1, fr2, lsum, lcnt);

    for (int off = 32; off; off >>= 1) {
        lsum += __shfl_down(lsum, off, 64);
        lcnt += __shfl_down(lcnt, off, 64);
    }
    if (lane == 0) {
        if (pairs) {
            pairs[ser] = make_double2(lsum, lcnt);
        } else {
            atomicAdd(&acc[1], lsum);
            atomicAdd(&acc[2], lcnt);
        }
    }
}

// ---------------------------------------------------------------------------
// Final reduction over per-block triples (ls, lc, ms): 123 KB read.
// ---------------------------------------------------------------------------
__global__ __launch_bounds__(1024) void reduce3_k(const double* __restrict__ blkout,
                                                  float* __restrict__ out) {
    const int tid = threadIdx.x;
    double ls = 0.0, lc = 0.0, ms = 0.0;
    for (int i = tid; i < NPATB; i += 1024) {
        ls += blkout[3 * i + 0];
        lc += blkout[3 * i + 1];
        ms += blkout[3 * i + 2];
    }
    for (int off = 32; off; off >>= 1) {
        ls += __shfl_down(ls, off, 64);
        lc += __shfl_down(lc, off, 64);
        ms += __shfl_down(ms, off, 64);
    }
    __shared__ double sl[16], sc[16], sm[16];
    int lane = tid & 63, wid = tid >> 6;
    if (lane == 0) { sl[wid] = ls; sc[wid] = lc; sm[wid] = ms; }
    __syncthreads();
    if (tid == 0) {
        double L = 0, C = 0, M = 0;
        for (int i = 0; i < 16; i++) { L += sl[i]; C += sc[i]; M += sm[i]; }
        double mse = M / (double)((size_t)NB * TT * NF);
        double avg = (C > 0.0) ? (L / C) : 0.0;
        out[0] = (float)(0.5 * mse + 0.5 * avg);
    }
}

// fallback reduce over pairs+msep (round-3 style)
__global__ __launch_bounds__(1024) void reduce_k(const double2* __restrict__ pairs,
                                                 const double* __restrict__ msep,
                                                 int nmse,
                                                 float* __restrict__ out) {
    const int tid = threadIdx.x;
    double ls = 0.0, lc = 0.0, ms = 0.0;
    for (int i = tid; i < NSER; i += 1024) {
        double2 p = pairs[i];
        ls += p.x; lc += p.y;
    }
    for (int i = tid; i < nmse; i += 1024) ms += msep[i];
    for (int off = 32; off; off >>= 1) {
        ls += __shfl_down(ls, off, 64);
        lc += __shfl_down(lc, off, 64);
        ms += __shfl_down(ms, off, 64);
    }
    __shared__ double sl[16], sc[16], sm[16];
    int lane = tid & 63, wid = tid >> 6;
    if (lane == 0) { sl[wid] = ls; sc[wid] = lc; sm[wid] = ms; }
    __syncthreads();
    if (tid == 0) {
        double L = 0, C = 0, M = 0;
        for (int i = 0; i < 16; i++) { L += sl[i]; C += sc[i]; M += sm[i]; }
        double mse = M / (double)((size_t)NB * TT * NF);
        double avg = (C > 0.0) ? (L / C) : 0.0;
        out[0] = (float)(0.5 * mse + 0.5 * avg);
    }
}

__global__ void finalize_k(const double* __restrict__ acc, float* __restrict__ out) {
    double mse = acc[0] / (double)((size_t)NB * TT * NF);
    double avg = (acc[2] > 0.0) ? (acc[1] / acc[2]) : 0.0;
    out[0] = (float)(0.5 * mse + 0.5 * avg);
}

// ---------------------------------------------------------------------------
extern "C" void kernel_launch(void* const* d_in, const int* in_sizes, int n_in,
                              void* d_out, int out_size, void* d_ws, size_t ws_size,
                              hipStream_t stream) {
    const float* fc = (const float*)d_in[0];   // forecast
    const float* tg = (const float*)d_in[1];   // target
    float* out = (float*)d_out;
    char* ws = (char*)d_ws;
    double* acc = (double*)ws;

    // layout: [0,64) acc | msep | blkout/pairs | topk | Wb | (fallback tsT)
    const size_t OFF_MSE = 64;
    const size_t OFF_PAIR = OFF_MSE + (size_t)NMSEP * sizeof(double);        // 62016
    const size_t OFF_TOP = OFF_PAIR + (size_t)NSER * sizeof(double2);        // 390720
    const size_t OFF_W = OFF_TOP + (size_t)NSER * sizeof(uint4);             // 719424
    const size_t OFF_END2 = OFF_W + (size_t)TT * KP * sizeof(unsigned short);// 955968
    const size_t bytesT = (size_t)NSER * TT * sizeof(float2);
    const bool big2 = (ws_size >= OFF_END2);                   // main path
    const size_t R3_OFF_TS = OFF_PAIR + (size_t)NSER * sizeof(double2);
    const bool big = !big2 && (ws_size >= R3_OFF_TS + bytesT);
    const bool mid = !big2 && !big && (ws_size >= OFF_MSE + bytesT);

    double* msep = (double*)(ws + OFF_MSE);
    double* blkout = (double*)(ws + OFF_PAIR);   // 3*NPATB doubles (123 KB)
    uint4* topkBuf = (uint4*)(ws + OFF_TOP);
    unsigned short* Wb = (unsigned short*)(ws + OFF_W);

    dim3 tg_grid(TGX, TGY, NB);
    dim3 tg_blk(32, 8);

    if (big2) {
        twiddle_k<<<TT, 128, 0, stream>>>(Wb);
        psd_k<<<NPSBG, 256, 0, stream>>>(tg, Wb, topkBuf);
        patch_k<<<NPATB, 64 * WPB, 0, stream>>>(fc, tg, topkBuf, blkout);
        reduce3_k<<<1, 1024, 0, stream>>>(blkout, out);
    } else if (big) {
        float2* tsT = (float2*)(ws + R3_OFF_TS);
        transpose_k<<<tg_grid, tg_blk, 0, stream>>>(fc, tg, tsT, msep, acc);
        series_k<<<NSER / WPB, 64 * WPB, 0, stream>>>(tsT, fc, tg, 1,
                                                      (double2*)blkout, acc);
        reduce_k<<<1, 1024, 0, stream>>>((double2*)blkout, msep, NMSEP, out);
    } else if (mid) {
        float2* tsT = (float2*)(ws + OFF_MSE);
        hipMemsetAsync(d_ws, 0, 64, stream);
        transpose_k<<<tg_grid, tg_blk, 0, stream>>>(fc, tg, tsT, nullptr, acc);
        series_k<<<NSER / WPB, 64 * WPB, 0, stream>>>(tsT, fc, tg, 1, nullptr, acc);
        finalize_k<<<1, 1, 0, stream>>>(acc, out);
    } else {
        hipMemsetAsync(d_ws, 0, 64, stream);
        mse_k<<<1024, 256, 0, stream>>>(fc, tg, acc);
        series_k<<<NSER / WPB, 64 * WPB, 0, stream>>>(nullptr, fc, tg, 0, nullptr, acc);
        finalize_k<<<1, 1, 0, stream>>>(acc, out);
    }
}

// Round 16
// 158.661 us; speedup vs baseline: 1.1888x; 1.1888x over previous
//
#include <hip/hip_runtime.h>
#include <hip/hip_bf16.h>

#define TT 336
#define NF 321
#define NB 64
#define NSER (NB * NF)   // 20544 series
#define WPB 4            // waves (series) per block in patch kernels
#define KP 352           // K padded to multiple of 32 for 16x16x32 MFMA
#define LDA 360          // LDS row stride (ushorts) in psd_k
#define SPB 16           // series per block in psd_k
#define NPSB (NSER / SPB)    // 1284 logical psd blocks
#define NPSBG 1288           // dispatched psd blocks (8 x 161, guard skips 4)
#define NPATB (NSER / WPB)   // 5136 patch blocks (divisible by 8)
#define TSP (TT + 4)     // padded ts row stride (float2): 680 words % 32 = 8

// prefix-table skew: breaks stride-P bank conflicts (P=16/32 worst cases)
#define SK(b) ((b) + ((b) >> 5))
#define TBL 348          // >= SK(336)+1 = 347

// transpose grid (fallback paths): 11 x 11 x 64 blocks
#define TGX 11
#define TGY 11
#define NMSEP (TGX * TGY * NB)   // 7744 per-block MSE partials (fallback)

typedef __attribute__((ext_vector_type(8))) short bf16x8;
typedef __attribute__((ext_vector_type(4))) float f32x4;
typedef unsigned long long ULL;

__device__ __forceinline__ unsigned short f2bf(float v) {
    unsigned x = __float_as_uint(v);
    x += 0x7FFFu + ((x >> 16) & 1u);   // RNE; inputs are finite
    return (unsigned short)(x >> 16);
}

// sorted-3 insert (a0 >= a1 >= a2)
__device__ __forceinline__ void ins3(ULL& a0, ULL& a1, ULL& a2, ULL x) {
    ULL hi = a0 > x ? a0 : x;
    ULL lo = a0 > x ? x : a0;
    a0 = hi;
    ULL hi1 = a1 > lo ? a1 : lo;
    ULL lo1 = a1 > lo ? lo : a1;
    a1 = hi1;
    a2 = a2 > lo1 ? a2 : lo1;
}

// ---------------------------------------------------------------------------
// Twiddle matrix: Wb[n][k], n=2(f-1) -> cos(2pi f k/336), n=2(f-1)+1 -> sin.
// fp32 trig: output is bf16 (8 mantissa bits) -> fp32 accuracy is exact here.
// ---------------------------------------------------------------------------
__global__ void twiddle_k(unsigned short* __restrict__ Wb) {
    int n = blockIdx.x;          // 0..335
    int f = (n >> 1) + 1;
    int isSin = n & 1;
    for (int k = threadIdx.x; k < KP; k += blockDim.x) {
        float v = 0.0f;
        if (k < TT) {
            int r = (f * k) % TT;
            float ang = 6.2831853071795864769f * (float)r / 336.0f;
            v = isSin ? sinf(ang) : cosf(ang);
        }
        Wb[(size_t)n * KP + k] = f2bf(v);
    }
}

// ---------------------------------------------------------------------------
// PSD + top-3 via MFMA GEMM. Block = 16 series, 4 waves split 21 nt-tiles
// (5/5/5/6); staging fully unrolled (natural VGPR budget — NO launch_bounds
// cap: r15 showed capping to 6 blocks/CU spills staging to scratch, 20.9 MB
// writes). XCD-aware swizzle kept (r15: FETCH 42 -> 25 MB, adjacent 16-series
// strips share unaligned 64B lines; same-XCD L2 absorbs them).
// ---------------------------------------------------------------------------
__global__ __launch_bounds__(256) void psd_k(const float* __restrict__ tgO,
                                             const unsigned short* __restrict__ Wb,
                                             uint4* __restrict__ topk) {
    __shared__ __align__(16) unsigned short sA[SPB][LDA];
    __shared__ ULL tk3[4][SPB][3];
    const int tid = threadIdx.x;
    const int lb = (blockIdx.x & 7) * 161 + (blockIdx.x >> 3);
    if (lb >= NPSB) return;
    const int serBase = lb * SPB;

    {
        int f_l = tid & 15, tch = tid >> 4;   // 16 t-chunks of 21
        int ser = serBase + f_l;
        int bb = ser / NF, ff = ser - bb * NF;
        const float* base = tgO + (size_t)bb * TT * NF + ff;
        int t0 = tch * 21;
        float v[21];
#pragma unroll
        for (int i = 0; i < 21; i++) v[i] = base[(size_t)(t0 + i) * NF];
#pragma unroll
        for (int i = 0; i < 21; i++) sA[f_l][t0 + i] = f2bf(v[i]);
    }
    if (tid < SPB * 16) sA[tid >> 4][TT + (tid & 15)] = 0;   // K padding
    __syncthreads();

    const int wave = tid >> 6, lane = tid & 63;
    const int quad = lane >> 4, c = lane & 15;
    const unsigned short* aRow = &sA[c][quad * 8];   // A[m=c][k=quad*8+j]
    const int ntStart = wave * 5;
    const int ntEnd = (wave == 3) ? 21 : ntStart + 5;

    ULL t0k[4] = {0, 0, 0, 0}, t1k[4] = {0, 0, 0, 0}, t2k[4] = {0, 0, 0, 0};
    for (int nt = ntStart; nt < ntEnd; nt++) {
        const unsigned short* bRow = Wb + (size_t)(nt * 16 + c) * KP + quad * 8;
        f32x4 acc = (f32x4){0.f, 0.f, 0.f, 0.f};
#pragma unroll
        for (int ks = 0; ks < 11; ks++) {
            bf16x8 a = *(const bf16x8*)(aRow + ks * 32);
            bf16x8 b = *(const bf16x8*)(bRow + ks * 32);
            acc = __builtin_amdgcn_mfma_f32_16x16x32_bf16(a, b, acc, 0, 0, 0);
        }
        int n = nt * 16 + c;
        unsigned fidx = (unsigned)((n >> 1) + 1);
        unsigned ftag = 0xFFFFFFFFu - fidx;
        bool odd = (n & 1) != 0;
#pragma unroll
        for (int r = 0; r < 4; r++) {
            float v = acc[r];
            float p = v * v;
            p += __shfl_xor(p, 1, 64);            // pair cos/sin columns
            ULL key = odd ? 0ull
                          : (((ULL)__float_as_uint(p) << 32) | (ULL)ftag);
            ins3(t0k[r], t1k[r], t2k[r], key);
        }
    }
#pragma unroll
    for (int m = 2; m <= 8; m <<= 1) {
#pragma unroll
        for (int r = 0; r < 4; r++) {
            ULL b0 = __shfl_xor(t0k[r], m, 64);
            ULL b1 = __shfl_xor(t1k[r], m, 64);
            ULL b2 = __shfl_xor(t2k[r], m, 64);
            ins3(t0k[r], t1k[r], t2k[r], b0);
            ins3(t0k[r], t1k[r], t2k[r], b1);
            ins3(t0k[r], t1k[r], t2k[r], b2);
        }
    }
    if (c == 0) {
#pragma unroll
        for (int r = 0; r < 4; r++) {
            int s = quad * 4 + r;
            tk3[wave][s][0] = t0k[r];
            tk3[wave][s][1] = t1k[r];
            tk3[wave][s][2] = t2k[r];
        }
    }
    __syncthreads();
    if (tid < SPB) {
        ULL k0 = 0, k1 = 0, k2 = 0;
#pragma unroll
        for (int wv = 0; wv < 4; wv++) {
#pragma unroll
            for (int j = 0; j < 3; j++) ins3(k0, k1, k2, tk3[wv][tid][j]);
        }
        unsigned f0 = 0xFFFFFFFFu - (unsigned)(k0 & 0xFFFFFFFFull);
        unsigned f1 = 0xFFFFFFFFu - (unsigned)(k1 & 0xFFFFFFFFull);
        unsigned f2 = 0xFFFFFFFFu - (unsigned)(k2 & 0xFFFFFFFFull);
        topk[serBase + tid] = make_uint4(f0, f1, f2, 0u);
    }
}

// ---------------------------------------------------------------------------
// FALLBACK Kernel: transpose [B,T,F] -> float2{tg,fc}[B*F][T], fused MSE.
// ---------------------------------------------------------------------------
__global__ __launch_bounds__(256) void transpose_k(const float* __restrict__ fc,
                                                   const float* __restrict__ tg,
                                                   float2* __restrict__ out,
                                                   double* __restrict__ msep,
                                                   double* __restrict__ acc) {
    __shared__ float ta[32][33];
    __shared__ float tb[32][33];
    __shared__ double wacc[4];
    const int b = blockIdx.z;
    const int t0 = blockIdx.x * 32, f0 = blockIdx.y * 32;
    const int tx = threadIdx.x, ty = threadIdx.y;   // block (32, 8)
    const size_t base = (size_t)b * TT * NF;
    double ms = 0.0;
#pragma unroll
    for (int k = 0; k < 4; k++) {
        int t = t0 + ty + 8 * k, f = f0 + tx;
        if (t < TT && f < NF) {
            float a = tg[base + (size_t)t * NF + f];
            float c = fc[base + (size_t)t * NF + f];
            ta[ty + 8 * k][tx] = a;
            tb[ty + 8 * k][tx] = c;
            double d = (double)a - (double)c;
            ms += d * d;
        }
    }
    __syncthreads();
#pragma unroll
    for (int k = 0; k < 4; k++) {
        int f = f0 + ty + 8 * k, t = t0 + tx;
        if (t < TT && f < NF) {
            out[((size_t)b * NF + f) * TT + t] =
                make_float2(ta[tx][ty + 8 * k], tb[tx][ty + 8 * k]);
        }
    }
    for (int off = 32; off; off >>= 1) ms += __shfl_down(ms, off, 64);
    int flat = ty * 32 + tx;
    int lane = flat & 63, wid = flat >> 6;
    if (lane == 0) wacc[wid] = ms;
    __syncthreads();
    if (flat == 0) {
        double tot = wacc[0] + wacc[1] + wacc[2] + wacc[3];
        if (msep) {
            int blk = (blockIdx.z * TGY + blockIdx.y) * TGX + blockIdx.x;
            msep[blk] = tot;
        } else {
            atomicAdd(&acc[0], tot);
        }
    }
}

// ---------------------------------------------------------------------------
__global__ void mse_k(const float* __restrict__ fc, const float* __restrict__ tg,
                      double* __restrict__ acc) {
    const size_t N4 = (size_t)NB * TT * NF / 4;
    const float4* a4 = (const float4*)fc;
    const float4* b4 = (const float4*)tg;
    double s = 0.0;
    for (size_t i = (size_t)blockIdx.x * blockDim.x + threadIdx.x; i < N4;
         i += (size_t)gridDim.x * blockDim.x) {
        float4 a = a4[i], b = b4[i];
        double d0 = (double)a.x - (double)b.x;
        double d1 = (double)a.y - (double)b.y;
        double d2 = (double)a.z - (double)b.z;
        double d3 = (double)a.w - (double)b.w;
        s += d0 * d0 + d1 * d1 + d2 * d2 + d3 * d3;
    }
    for (int off = 32; off; off >>= 1) s += __shfl_down(s, off, 64);
    __shared__ double wsum[4];
    int flat = threadIdx.x;
    int lane = flat & 63, wid = flat >> 6;
    if (lane == 0) wsum[wid] = s;
    __syncthreads();
    if (flat == 0) atomicAdd(&acc[0], wsum[0] + wsum[1] + wsum[2] + wsum[3]);
}

// ---------------------------------------------------------------------------
// Full-fp64 patch loss (fallback path — exact reference mirror)
// ---------------------------------------------------------------------------
__device__ __forceinline__ double patch_loss(double S1, double S2, double S3,
                                             double S4, double S5, double nn) {
    double mt = S1 / nn, mf = S2 / nn;
    double tvs = S3 - nn * mt * mt; tvs = tvs > 0.0 ? tvs : 0.0;
    double fvs = S4 - nn * mf * mf; fvs = fvs > 0.0 ? fvs : 0.0;
    double num = S5 - nn * mt * mf;
    double corr = num / (sqrt(tvs * fvs) + 1e-8);
    double closs = 1.0 - fabs(corr);
    double tvar = tvs / (nn - 1.0), fvar = fvs / (nn - 1.0);
    double vloss = fabs(tvar - fvar) / (tvar + 1e-8);
    double mloss = fabs(mt - mf) / (fabs(mt) + 1e-8);
    return closs + vloss + mloss;
}

// ---------------------------------------------------------------------------
// Round-10 fast patch loss: closs/vloss fp32, mloss fp64 (one fp64 divide).
// ---------------------------------------------------------------------------
__device__ __forceinline__ double patch_loss_fast(double S1, double S2,
                                                  float S3, float S4, float S5,
                                                  int n) {
    float nnf = (float)n;
    float invf = 1.0f / nnf;
    float s1f = (float)S1, s2f = (float)S2;
    float tvs = S3 - s1f * s1f * invf; tvs = tvs > 0.f ? tvs : 0.f;
    float fvs = S4 - s2f * s2f * invf; fvs = fvs > 0.f ? fvs : 0.f;
    float num = S5 - s1f * s2f * invf;
    float corr = num / (sqrtf(tvs * fvs) + 1e-8f);
    float closs = 1.0f - fabsf(corr);
    float vloss = fabsf(tvs - fvs) / (tvs + (nnf - 1.0f) * 1e-8f);
    double mloss = fabs(S1 - S2) / (fabs(S1) + (double)n * 1e-8);
    return (double)(closs + vloss) + mloss;
}

// ---------------------------------------------------------------------------
struct PatchCfg {
    int P[3], nseg[3], rs[3];
    bool vp[3], hr[3];
};

__device__ __forceinline__ void make_cfg(int fr0, int fr1, int fr2, PatchCfg& c) {
    c.P[0] = TT / fr0; c.P[1] = TT / fr1; c.P[2] = TT / fr2;
    c.vp[0] = (c.P[0] >= 5);
    c.vp[1] = (c.P[1] >= 5) && (c.P[1] != c.P[0]);
    c.vp[2] = (c.P[2] >= 5) && (c.P[2] != c.P[0]) && (c.P[2] != c.P[1]);
#pragma unroll
    for (int q = 0; q < 3; q++) {
        c.nseg[q] = TT / c.P[q];
        c.rs[q] = c.nseg[q] * c.P[q];
        c.hr[q] = c.vp[q] && ((TT - c.rs[q]) >= 5);
    }
}

// slot i in [0,204) -> (s,e,kept) with dedup against earlier periods
__device__ __forceinline__ bool slot_patch(const PatchCfg& c, int i, int& s, int& e) {
    bool kept = false;
    s = 0; e = 0;
    if (i < 204) {
        int k = (i >= 136) ? 2 : ((i >= 68) ? 1 : 0);
        int si = i - k * 68;
        if (c.vp[k]) {
            if (si < c.nseg[k]) { s = c.P[k] * si; e = s + c.P[k]; kept = true; }
            else if (si == c.nseg[k] && c.hr[k]) { s = c.rs[k]; e = TT; kept = true; }
            if (kept) {
#pragma unroll
                for (int j = 0; j < 2; j++) {
                    if (j < k && c.vp[j]) {
                        bool dup = (s == c.rs[j]) && (e == TT) && c.hr[j];
                        int len = e - s;
                        if (len == c.P[j] && s < c.rs[j] && (s % c.P[j]) == 0) dup = true;
                        if (dup) kept = false;
                    }
                }
            }
        }
    }
    return kept;
}

// ---------------------------------------------------------------------------
// Kernel (round-10 verified body): patch stats from ORIGINAL layout with
// fused MSE. XCD swizzle; ts rows padded to TSP; S1,S2 fp64 tables;
// S3..S5 fp32. Epilogue: block-level LDS reduce -> ONE (ls,lc,ms) triple.
// ---------------------------------------------------------------------------
__global__ __launch_bounds__(256) void patch_k(const float* __restrict__ fcO,
                                               const float* __restrict__ tgO,
                                               const uint4* __restrict__ topk,
                                               double* __restrict__ blkout) {
    __shared__ __align__(16) char smem[2 * WPB * TBL * 8 + 3 * WPB * TBL * 4];
    double (*d1)[TBL] = (double(*)[TBL])smem;
    double (*d2)[TBL] = (double(*)[TBL])(smem + WPB * TBL * 8);
    char* regB = smem + 2 * WPB * TBL * 8;
    float2* tsB = (float2*)regB;                   // rows of stride TSP
    float (*t3)[TBL] = (float(*)[TBL])regB;
    float (*t4)[TBL] = (float(*)[TBL])(regB + WPB * TBL * 4);
    float (*t5)[TBL] = (float(*)[TBL])(regB + 2 * WPB * TBL * 4);
    __shared__ double wms[WPB], wls[WPB], wlc[WPB];

    const int tid = threadIdx.x;
    const int w = tid >> 6, lane = tid & 63;
    const int lb = (blockIdx.x & 7) * (NPATB / 8) + (blockIdx.x >> 3);
    const int ser = lb * WPB + w;

    // ---- cooperative load from original layout + fused MSE ----
    {
        const int j = tid & 3;
        const int serj = lb * WPB + j;
        const int bb = serj / NF, ff = serj - bb * NF;
        const float* tb_ = tgO + (size_t)bb * TT * NF + ff;
        const float* fb_ = fcO + (size_t)bb * TT * NF + ff;
        const int tb0 = tid >> 2;
        float2* row = tsB + j * TSP;
        double ms = 0.0;
#pragma unroll
        for (int i = 0; i < 6; i++) {
            int t = tb0 + 64 * i;
            if (t < TT) {
                float a = tb_[(size_t)t * NF];
                float c = fb_[(size_t)t * NF];
                row[t] = make_float2(a, c);
                double d = (double)a - (double)c;
                ms += d * d;
            }
        }
        for (int off = 32; off; off >>= 1) ms += __shfl_down(ms, off, 64);
        if (lane == 0) wms[w] = ms;
    }
    __syncthreads();

    // ---- each wave pulls its series' 6 elements/lane into registers ----
    float2 loc[6];
    double c1 = 0, c2 = 0;
    float c3 = 0, c4 = 0, c5 = 0;
    if (lane < 56) {
        const float4* lp = (const float4*)(tsB + w * TSP + 6 * lane);  // 48B
        float4 va = lp[0], vb = lp[1], vc = lp[2];
        loc[0] = make_float2(va.x, va.y); loc[1] = make_float2(va.z, va.w);
        loc[2] = make_float2(vb.x, vb.y); loc[3] = make_float2(vb.z, vb.w);
        loc[4] = make_float2(vc.x, vc.y); loc[5] = make_float2(vc.z, vc.w);
#pragma unroll
        for (int i = 0; i < 6; i++) {
            float a = loc[i].x, b = loc[i].y;
            c1 += (double)a; c2 += (double)b;
            c3 = fmaf(a, a, c3); c4 = fmaf(b, b, c4); c5 = fmaf(a, b, c5);
        }
    }

    // ---- inclusive scan over chunk sums (S1,S2 fp64; S3..S5 fp32) ----
    double s1 = c1, s2 = c2;
    float s3 = c3, s4 = c4, s5 = c5;
#pragma unroll
    for (int off = 1; off < 64; off <<= 1) {
        double y1 = __shfl_up(s1, off, 64);
        double y2 = __shfl_up(s2, off, 64);
        float y3 = __shfl_up(s3, off, 64);
        float y4 = __shfl_up(s4, off, 64);
        float y5 = __shfl_up(s5, off, 64);
        if (lane >= off) { s1 += y1; s2 += y2; s3 += y3; s4 += y4; s5 += y5; }
    }

    __syncthreads();   // everyone done reading ts before tables overlay it

    // ---- write per-element prefix table (skewed index) ----
    if (lane == 63) {
        d1[w][SK(0)] = 0.0; d2[w][SK(0)] = 0.0;
        t3[w][SK(0)] = 0.f; t4[w][SK(0)] = 0.f; t5[w][SK(0)] = 0.f;
    }
    if (lane < 56) {
        double r1 = s1 - c1, r2 = s2 - c2;
        float r3 = s3 - c3, r4 = s4 - c4, r5 = s5 - c5;
#pragma unroll
        for (int i = 0; i < 6; i++) {
            float a = loc[i].x, b = loc[i].y;
            r1 += (double)a; r2 += (double)b;
            r3 = fmaf(a, a, r3); r4 = fmaf(b, b, r4); r5 = fmaf(a, b, r5);
            int ix = SK(6 * lane + i + 1);
            d1[w][ix] = r1; d2[w][ix] = r2;
            t3[w][ix] = r3; t4[w][ix] = r4; t5[w][ix] = r5;
        }
    }
    __syncthreads();

    uint4 tk = topk[ser];
    PatchCfg cfg;
    make_cfg((int)tk.x, (int)tk.y, (int)tk.z, cfg);

    double lsum = 0.0, lcnt = 0.0;
    ULL anyMask = 0ull;
#pragma unroll
    for (int rI = 0; rI < 4; rI++) {
        int s, e;
        bool kept = slot_patch(cfg, lane + 64 * rI, s, e);
        ULL bal = __ballot(kept);
        anyMask |= bal;
        if (bal == 0ull) continue;          // wave-uniform early-out
        if (kept) {
            int is = SK(s), ie = SK(e);
            double S1 = d1[w][ie] - d1[w][is];
            double S2 = d2[w][ie] - d2[w][is];
            float S3 = t3[w][ie] - t3[w][is];
            float S4 = t4[w][ie] - t4[w][is];
            float S5 = t5[w][ie] - t5[w][is];
            lsum += patch_loss_fast(S1, S2, S3, S4, S5, e - s);
            lcnt += 1.0;
        }
    }

    if (anyMask == 0ull) {
        if (lane == 0) {
            int ie = SK(TT);
            lsum += patch_loss_fast(d1[w][ie], d2[w][ie], t3[w][ie],
                                    t4[w][ie], t5[w][ie], TT);
            lcnt += 1.0;
        }
    }

    for (int off = 32; off; off >>= 1) {
        lsum += __shfl_down(lsum, off, 64);
        lcnt += __shfl_down(lcnt, off, 64);
    }
    if (lane == 0) { wls[w] = lsum; wlc[w] = lcnt; }
    __syncthreads();
    if (tid == 0) {
        blkout[3 * lb + 0] = wls[0] + wls[1] + wls[2] + wls[3];
        blkout[3 * lb + 1] = wlc[0] + wlc[1] + wlc[2] + wlc[3];
        blkout[3 * lb + 2] = wms[0] + wms[1] + wms[2] + wms[3];
    }
}

// ---------------------------------------------------------------------------
// FALLBACK: self-contained series kernel (VALU DFT + topk + serial patches).
// ---------------------------------------------------------------------------
__device__ __forceinline__ void patch_body(const float2* tsw, int lane,
                                           int fr0, int fr1, int fr2,
                                           double& lsum, double& lcnt) {
    PatchCfg cfg;
    make_cfg(fr0, fr1, fr2, cfg);
    ULL anyMask = 0ull;
#pragma unroll
    for (int rI = 0; rI < 4; rI++) {
        int s, e;
        bool kept = slot_patch(cfg, lane + 64 * rI, s, e);
        anyMask |= __ballot(kept);
        if (kept) {
            double S1 = 0, S2 = 0, S3 = 0, S4 = 0, S5 = 0;
            for (int t = s; t < e; t++) {
                float2 v = tsw[t];
                double a = (double)v.x, b = (double)v.y;
                S1 += a; S2 += b;
                S3 += a * a; S4 += b * b; S5 += a * b;
            }
            lsum += patch_loss(S1, S2, S3, S4, S5, (double)(e - s));
            lcnt += 1.0;
        }
    }
    if (anyMask == 0ull) {
        double S1 = 0, S2 = 0, S3 = 0, S4 = 0, S5 = 0;
        for (int t = lane; t < TT; t += 64) {
            float2 v = tsw[t];
            double a = (double)v.x, b = (double)v.y;
            S1 += a; S2 += b;
            S3 += a * a; S4 += b * b; S5 += a * b;
        }
        for (int off = 32; off; off >>= 1) {
            S1 += __shfl_down(S1, off, 64);
            S2 += __shfl_down(S2, off, 64);
            S3 += __shfl_down(S3, off, 64);
            S4 += __shfl_down(S4, off, 64);
            S5 += __shfl_down(S5, off, 64);
        }
        if (lane == 0) {
            lsum += patch_loss(S1, S2, S3, S4, S5, (double)TT);
            lcnt += 1.0;
        }
    }
}

__global__ __launch_bounds__(256, 6) void series_k(const float2* __restrict__ tsG,
                                                   const float* __restrict__ fcG,
                                                   const float* __restrict__ tgG,
                                                   int transposed,
                                                   double2* __restrict__ pairs,
                                                   double* __restrict__ acc) {
    const int w = threadIdx.x >> 6, lane = threadIdx.x & 63;
    const int ser = blockIdx.x * WPB + w;
    __shared__ float2 ts[WPB][TT];
    __shared__ float4 zb[WPB][84];

    if (transposed) {
        const float2* sp = tsG + (size_t)ser * TT;
        for (int t = lane; t < TT; t += 64) ts[w][t] = sp[t];
    } else {
        int b = ser / NF, f = ser - b * NF;
        const float* tp = tgG + (size_t)b * TT * NF + f;
        const float* fp = fcG + (size_t)b * TT * NF + f;
        for (int t = lane; t < TT; t += 64)
            ts[w][t] = make_float2(tp[(size_t)t * NF], fp[(size_t)t * NF]);
    }
    __syncthreads();

    for (int t = lane; t < 84; t += 64) {
        float x0 = ts[w][t].x, x1 = ts[w][t + 84].x;
        float x2 = ts[w][t + 168].x, x3 = ts[w][t + 252].x;
        float a = x0 + x2, b2 = x1 + x3, c = x0 - x2, d = x1 - x3;
        zb[w][t] = make_float4(a + b2, a - b2, c, d);
    }
    __syncthreads();

    const double TWOPI = 6.283185307179586476925286766559;
    int fb[3] = {1 + lane, 65 + lane, 129 + lane};
    float cc[3], sn[3], re[3], im[3], cd[3], sd[3], sgn[3];
    int selA[3];
#pragma unroll
    for (int q = 0; q < 3; q++) {
        int f = fb[q], cls = f & 3;
        double dl = (double)f * (TWOPI / 336.0);
        cd[q] = (float)cos(dl);
        sd[q] = (float)sin(dl);
        cc[q] = 1.0f; sn[q] = 0.0f; re[q] = 0.0f; im[q] = 0.0f;
        sgn[q] = (cls == 1) ? -1.0f : ((cls == 3) ? 1.0f : 0.0f);
        selA[q] = (cls == 0) ? 0 : ((cls == 2) ? 1 : 2);
    }
    for (int t = 0; t < 84; t++) {
        float4 zv = zb[w][t];
#pragma unroll
        for (int q = 0; q < 3; q++) {
            float zr = (selA[q] == 0) ? zv.x : ((selA[q] == 1) ? zv.y : zv.z);
            float zi = sgn[q] * zv.w;
            re[q] = fmaf(zr, cc[q], re[q]);
            re[q] = fmaf(zi, sn[q], re[q]);
            im[q] = fmaf(zi, cc[q], im[q]);
            im[q] = fmaf(-zr, sn[q], im[q]);
            float nc = fmaf(cc[q], cd[q], -(sn[q] * sd[q]));
            float ns = fmaf(sn[q], cd[q], cc[q] * sd[q]);
            cc[q] = nc; sn[q] = ns;
        }
    }

    ULL k0 = 0, k1 = 0, k2 = 0;
#pragma unroll
    for (int q = 0; q < 3; q++) {
        float a2 = fmaf(re[q], re[q], im[q] * im[q]);
        ULL key = ((ULL)__float_as_uint(a2) << 32) |
                  (ULL)(0xFFFFFFFFu - (unsigned)fb[q]);
        if (fb[q] > 168) key = 0ull;
        ins3(k0, k1, k2, key);
    }
    for (int m = 1; m < 64; m <<= 1) {
        ULL b0 = __shfl_xor(k0, m, 64);
        ULL b1 = __shfl_xor(k1, m, 64);
        ULL b2 = __shfl_xor(k2, m, 64);
        ins3(k0, k1, k2, b0); ins3(k0, k1, k2, b1); ins3(k0, k1, k2, b2);
    }

    int fr0 = (int)(0xFFFFFFFFu - (unsigned)(k0 & 0xFFFFFFFFull));
    int fr1 = (int)(0xFFFFFFFFu - (unsigned)(k1 & 0xFFFFFFFFull));
    int fr2 = (int)(0xFFFFFFFFu - (unsigned)(k2 & 0xFFFFFFFFull));

    double lsum = 0.0, lcnt = 0.0;
    patch_body(&ts[w][0], lane, fr0, fr1, fr2, lsum, lcnt);

    for (int off = 32; off; off >>= 1) {
        lsum += __shfl_down(lsum, off, 64);
        lcnt += __shfl_down(lcnt, off, 64);
    }
    if (lane == 0) {
        if (pairs) {
            pairs[ser] = make_double2(lsum, lcnt);
        } else {
            atomicAdd(&acc[1], lsum);
            atomicAdd(&acc[2], lcnt);
        }
    }
}

// ---------------------------------------------------------------------------
// Final reduction over per-block triples (ls, lc, ms): 123 KB read.
// ---------------------------------------------------------------------------
__global__ __launch_bounds__(1024) void reduce3_k(const double* __restrict__ blkout,
                                                  float* __restrict__ out) {
    const int tid = threadIdx.x;
    double ls = 0.0, lc = 0.0, ms = 0.0;
    for (int i = tid; i < NPATB; i += 1024) {
        ls += blkout[3 * i + 0];
        lc += blkout[3 * i + 1];
        ms += blkout[3 * i + 2];
    }
    for (int off = 32; off; off >>= 1) {
        ls += __shfl_down(ls, off, 64);
        lc += __shfl_down(lc, off, 64);
        ms += __shfl_down(ms, off, 64);
    }
    __shared__ double sl[16], sc[16], sm[16];
    int lane = tid & 63, wid = tid >> 6;
    if (lane == 0) { sl[wid] = ls; sc[wid] = lc; sm[wid] = ms; }
    __syncthreads();
    if (tid == 0) {
        double L = 0, C = 0, M = 0;
        for (int i = 0; i < 16; i++) { L += sl[i]; C += sc[i]; M += sm[i]; }
        double mse = M / (double)((size_t)NB * TT * NF);
        double avg = (C > 0.0) ? (L / C) : 0.0;
        out[0] = (float)(0.5 * mse + 0.5 * avg);
    }
}

// fallback reduce over pairs+msep (round-3 style)
__global__ __launch_bounds__(1024) void reduce_k(const double2* __restrict__ pairs,
                                                 const double* __restrict__ msep,
                                                 int nmse,
                                                 float* __restrict__ out) {
    const int tid = threadIdx.x;
    double ls = 0.0, lc = 0.0, ms = 0.0;
    for (int i = tid; i < NSER; i += 1024) {
        double2 p = pairs[i];
        ls += p.x; lc += p.y;
    }
    for (int i = tid; i < nmse; i += 1024) ms += msep[i];
    for (int off = 32; off; off >>= 1) {
        ls += __shfl_down(ls, off, 64);
        lc += __shfl_down(lc, off, 64);
        ms += __shfl_down(ms, off, 64);
    }
    __shared__ double sl[16], sc[16], sm[16];
    int lane = tid & 63, wid = tid >> 6;
    if (lane == 0) { sl[wid] = ls; sc[wid] = lc; sm[wid] = ms; }
    __syncthreads();
    if (tid == 0) {
        double L = 0, C = 0, M = 0;
        for (int i = 0; i < 16; i++) { L += sl[i]; C += sc[i]; M += sm[i]; }
        double mse = M / (double)((size_t)NB * TT * NF);
        double avg = (C > 0.0) ? (L / C) : 0.0;
        out[0] = (float)(0.5 * mse + 0.5 * avg);
    }
}

__global__ void finalize_k(const double* __restrict__ acc, float* __restrict__ out) {
    double mse = acc[0] / (double)((size_t)NB * TT * NF);
    double avg = (acc[2] > 0.0) ? (acc[1] / acc[2]) : 0.0;
    out[0] = (float)(0.5 * mse + 0.5 * avg);
}

// ---------------------------------------------------------------------------
extern "C" void kernel_launch(void* const* d_in, const int* in_sizes, int n_in,
                              void* d_out, int out_size, void* d_ws, size_t ws_size,
                              hipStream_t stream) {
    const float* fc = (const float*)d_in[0];   // forecast
    const float* tg = (const float*)d_in[1];   // target
    float* out = (float*)d_out;
    char* ws = (char*)d_ws;
    double* acc = (double*)ws;

    // layout: [0,64) acc | msep | blkout/pairs | topk | Wb | (fallback tsT)
    const size_t OFF_MSE = 64;
    const size_t OFF_PAIR = OFF_MSE + (size_t)NMSEP * sizeof(double);        // 62016
    const size_t OFF_TOP = OFF_PAIR + (size_t)NSER * sizeof(double2);        // 390720
    const size_t OFF_W = OFF_TOP + (size_t)NSER * sizeof(uint4);             // 719424
    const size_t OFF_END2 = OFF_W + (size_t)TT * KP * sizeof(unsigned short);// 955968
    const size_t bytesT = (size_t)NSER * TT * sizeof(float2);
    const bool big2 = (ws_size >= OFF_END2);                   // main path
    const size_t R3_OFF_TS = OFF_PAIR + (size_t)NSER * sizeof(double2);
    const bool big = !big2 && (ws_size >= R3_OFF_TS + bytesT);
    const bool mid = !big2 && !big && (ws_size >= OFF_MSE + bytesT);

    double* msep = (double*)(ws + OFF_MSE);
    double* blkout = (double*)(ws + OFF_PAIR);   // 3*NPATB doubles (123 KB)
    uint4* topkBuf = (uint4*)(ws + OFF_TOP);
    unsigned short* Wb = (unsigned short*)(ws + OFF_W);

    dim3 tg_grid(TGX, TGY, NB);
    dim3 tg_blk(32, 8);

    if (big2) {
        twiddle_k<<<TT, 128, 0, stream>>>(Wb);
        psd_k<<<NPSBG, 256, 0, stream>>>(tg, Wb, topkBuf);
        patch_k<<<NPATB, 64 * WPB, 0, stream>>>(fc, tg, topkBuf, blkout);
        reduce3_k<<<1, 1024, 0, stream>>>(blkout, out);
    } else if (big) {
        float2* tsT = (float2*)(ws + R3_OFF_TS);
        transpose_k<<<tg_grid, tg_blk, 0, stream>>>(fc, tg, tsT, msep, acc);
        series_k<<<NSER / WPB, 64 * WPB, 0, stream>>>(tsT, fc, tg, 1,
                                                      (double2*)blkout, acc);
        reduce_k<<<1, 1024, 0, stream>>>((double2*)blkout, msep, NMSEP, out);
    } else if (mid) {
        float2* tsT = (float2*)(ws + OFF_MSE);
        hipMemsetAsync(d_ws, 0, 64, stream);
        transpose_k<<<tg_grid, tg_blk, 0, stream>>>(fc, tg, tsT, nullptr, acc);
        series_k<<<NSER / WPB, 64 * WPB, 0, stream>>>(tsT, fc, tg, 1, nullptr, acc);
        finalize_k<<<1, 1, 0, stream>>>(acc, out);
    } else {
        hipMemsetAsync(d_ws, 0, 64, stream);
        mse_k<<<1024, 256, 0, stream>>>(fc, tg, acc);
        series_k<<<NSER / WPB, 64 * WPB, 0, stream>>>(nullptr, fc, tg, 0, nullptr, acc);
        finalize_k<<<1, 1, 0, stream>>>(acc, out);
    }
}